// Round 7
// baseline (103.803 us; speedup 1.0000x reference)
//
#include <hip/hip_runtime.h>

typedef __attribute__((ext_vector_type(8))) short bf16x8;
typedef __attribute__((ext_vector_type(16))) float f32x16;

#define SLEN 2048
#define DDIM 64
#define KEPS 1e-6f
#define STR 72                    // shorts per LDS row (144 B): 16B-aligned, uniform bank use
#define TILEB (64 * STR * 2)      // 9216 B per K or VT tile

// packed fp32x2 -> bf16x2 RNE, single VALU op
__device__ __forceinline__ unsigned cvtpk(float lo, float hi) {
    unsigned r;
    asm("v_cvt_pk_bf16_f32 %0, %1, %2" : "=v"(r) : "v"(lo), "v"(hi));
    return r;
}

__device__ __forceinline__ f32x16 mfma32x32(bf16x8 a, bf16x8 b, f32x16 c) {
    return __builtin_amdgcn_mfma_f32_32x32x16_bf16(a, b, c, 0, 0, 0);
}

// Rebased linear attention, causal, z = rowsum(s^2).
// 256 blocks x 1024 threads (1 block/CU, uniform work). Block = head h, q-groups
// {pg, 31-pg} (mirror INSIDE block -> all blocks equal work). 16 waves =
// 4 KV-parities x (2 q-groups x 2 halves); each wave owns 32 q-rows and computes
// its parity's KV tiles (kt = 4t+p) with 32x32x16 MFMA (swapped QK^T -> S^T),
// P repacked via cvt_pk + permlane32_swap (VALU only), PV 32x32x16 with b128 V reads.
// Double-buffered LDS per parity: ONE barrier per iteration.
__global__ void __launch_bounds__(1024, 4) rebased_attn_kernel(
    const float* __restrict__ Q, const float* __restrict__ K,
    const float* __restrict__ V, float* __restrict__ O)
{
    __shared__ __align__(16) char smem[16 * TILEB];   // 147456 B: [par][dbuf][K,VT]

    const int bid  = blockIdx.x;
    const int xcd  = bid & 7;                 // head pinned to XCD (KV stays in one L2)
    const int rest = bid >> 3;                // 0..31
    const int h    = xcd | ((rest & 1) << 3); // 0..15
    const int pg   = rest >> 1;               // mirror pair (pg, 31-pg), pg 0..15

    const int tid  = threadIdx.x;
    const int w    = tid >> 6;                // wave 0..15
    const int lane = tid & 63;
    const int il   = lane & 31;               // i-col within 32x32 fragments
    const int hi   = lane >> 5;
    const int p    = w >> 2;                  // KV parity 0..3 (== tid>>8)
    const int qw   = w & 3;
    const int qsel = qw >> 1;                 // 0 = light group pg, 1 = heavy 31-pg
    const int half = qw & 1;                  // which 32-row half of the 64-row group

    const int grp   = qsel ? (31 - pg) : pg;
    const int q0    = grp * 64 + half * 32;   // this wave's 32 q-rows
    const int ktmax = grp;                    // last KV 64-tile this wave touches
    const int ktstg = 31 - pg;                // last tile the block stages

    const float* __restrict__ Qh = Q + (size_t)h * SLEN * DDIM;
    const float* __restrict__ Kh = K + (size_t)h * SLEN * DDIM;
    const float* __restrict__ Vh = V + (size_t)h * SLEN * DDIM;
    float* __restrict__ Oh = O + (size_t)h * SLEN * DDIM;

    // ---- Q fragments (B-frag of 32x32x16): lane holds Q[q0+il][ks*16 + hi*8 + t] ----
    bf16x8 qf[4];
#pragma unroll
    for (int ks = 0; ks < 4; ++ks) {
        const float* src = Qh + (size_t)(q0 + il) * DDIM + ks * 16 + hi * 8;
        float4 a = *reinterpret_cast<const float4*>(src);
        float4 b = *reinterpret_cast<const float4*>(src + 4);
        uint4 u = make_uint4(cvtpk(a.x, a.y), cvtpk(a.z, a.w),
                             cvtpk(b.x, b.y), cvtpk(b.z, b.w));
        qf[ks] = *reinterpret_cast<bf16x8*>(&u);
    }

    f32x16 oacc[2];
#pragma unroll
    for (int dt = 0; dt < 2; ++dt)
#pragma unroll
        for (int r = 0; r < 16; ++r) oacc[dt][r] = 0.f;
    float zacc = 0.f;

    // ---- staging maps (per parity: 256 threads move one 64x64 K + V tile) ----
    const int t255 = tid & 255;
    const int kr  = t255 >> 2;            // K row 0..63
    const int kc  = (t255 & 3) * 16;      // K col chunk (floats)
    const int vj0 = (t255 & 15) * 4;      // V rows (j)
    const int vd0 = (t255 >> 4) * 4;      // V cols (d)

    short* const Kt[2] = { (short*)(smem + ((p * 2 + 0) * 2 + 0) * TILEB),
                           (short*)(smem + ((p * 2 + 1) * 2 + 0) * TILEB) };
    short* const Vt[2] = { (short*)(smem + ((p * 2 + 0) * 2 + 1) * TILEB),
                           (short*)(smem + ((p * 2 + 1) * 2 + 1) * TILEB) };

    float4 kv[4], vv[4];
    auto issue_loads = [&](int kt) {
        const float* ks = Kh + (size_t)(kt * 64 + kr) * DDIM + kc;
#pragma unroll
        for (int i = 0; i < 4; ++i) kv[i] = reinterpret_cast<const float4*>(ks)[i];
#pragma unroll
        for (int r = 0; r < 4; ++r)
            vv[r] = *reinterpret_cast<const float4*>(Vh + (size_t)(kt * 64 + vj0 + r) * DDIM + vd0);
    };
    auto write_lds = [&](int b) {
        short* kd = Kt[b] + kr * STR + kc;
        uint4 o0 = make_uint4(cvtpk(kv[0].x, kv[0].y), cvtpk(kv[0].z, kv[0].w),
                              cvtpk(kv[1].x, kv[1].y), cvtpk(kv[1].z, kv[1].w));
        uint4 o1 = make_uint4(cvtpk(kv[2].x, kv[2].y), cvtpk(kv[2].z, kv[2].w),
                              cvtpk(kv[3].x, kv[3].y), cvtpk(kv[3].z, kv[3].w));
        *reinterpret_cast<uint4*>(kd) = o0;
        *reinterpret_cast<uint4*>(kd + 8) = o1;
#pragma unroll
        for (int c = 0; c < 4; ++c) {
            uint2 pk = make_uint2(
                cvtpk(((const float*)&vv[0])[c], ((const float*)&vv[1])[c]),
                cvtpk(((const float*)&vv[2])[c], ((const float*)&vv[3])[c]));
            *reinterpret_cast<uint2*>(&Vt[b][(vd0 + c) * STR + vj0]) = pk;
        }
    };

    // one 32x32 j-subtile: QK^T (swapped) -> square/scale/mask -> pack -> PV
    auto subtile = [&](const short* kp, const short* vp, int jb, bool tri) {
        f32x16 s;
#pragma unroll
        for (int r = 0; r < 16; ++r) s[r] = 0.f;
#pragma unroll
        for (int ks = 0; ks < 4; ++ks) {
            bf16x8 kf = *reinterpret_cast<const bf16x8*>(
                kp + (jb * 32 + il) * STR + ks * 16 + hi * 8);
            s = mfma32x32(kf, qf[ks], s);
        }
        // lane holds S^T[j = (r&3)+8*(r>>2)+4*hi][i = il]; p = (s/8)^2 = s^2/64
#pragma unroll
        for (int r = 0; r < 16; ++r) {
            float x = s[r];
            x = x * x * 0.015625f;
            if (tri) {
                int jl = (r & 3) + 8 * (r >> 2) + 4 * hi;
                if (jl > il) x = 0.f;
            }
            s[r] = x;
            zacc += x;
        }
        // pack P into A-frags via cvt_pk + permlane32_swap; PV with b128 V reads
#pragma unroll
        for (int s16 = 0; s16 < 2; ++s16) {
            unsigned X  = cvtpk(s[8 * s16 + 0], s[8 * s16 + 1]);
            unsigned Xp = cvtpk(s[8 * s16 + 2], s[8 * s16 + 3]);
            unsigned Y  = cvtpk(s[8 * s16 + 4], s[8 * s16 + 5]);
            unsigned Yp = cvtpk(s[8 * s16 + 6], s[8 * s16 + 7]);
            asm("v_permlane32_swap_b32 %0, %1" : "+v"(X), "+v"(Y));
            asm("v_permlane32_swap_b32 %0, %1" : "+v"(Xp), "+v"(Yp));
            uint4 aw = make_uint4(X, Xp, Y, Yp);
            bf16x8 pf = *reinterpret_cast<bf16x8*>(&aw);
#pragma unroll
            for (int dt = 0; dt < 2; ++dt) {
                bf16x8 vf = *reinterpret_cast<const bf16x8*>(
                    vp + (dt * 32 + il) * STR + jb * 64 / 2 + s16 * 16 + hi * 8);
                oacc[dt] = mfma32x32(pf, vf, oacc[dt]);
            }
        }
    };

    const int T = (ktstg >> 2) + 1;

    // ---- prologue: stage tile kt=p into buf 0 ----
    issue_loads(p);
    write_lds(0);
    __syncthreads();

    for (int t = 0; t < T; ++t) {
        const int kt  = 4 * t + p;
        const int nxt = kt + 4;
        const int cur = t & 1;

        if (nxt <= ktstg) issue_loads(nxt);    // in flight during compute

        if (kt <= ktmax) {
            const short* kp = Kt[cur];
            const short* vp = Vt[cur];
            __builtin_amdgcn_s_setprio(1);
            if (kt < ktmax) {
                subtile(kp, vp, 0, false);
                subtile(kp, vp, 1, false);
            } else if (half == 0) {
                subtile(kp, vp, 0, true);      // diag in jsub0; jsub1 all-future
            } else {
                subtile(kp, vp, 0, false);     // jsub0 all-past
                subtile(kp, vp, 1, true);      // diag in jsub1
            }
            __builtin_amdgcn_s_setprio(0);
        }

        if (nxt <= ktstg) write_lds(cur ^ 1);
        __syncthreads();
    }

    // ---- combine 4 parity partials via LDS (stride-33 floats: conflict-free) ----
    zacc += __shfl_xor(zacc, 32);              // fold hi-half j's: z[i] per lane
    float* red = (float*)smem;
    if (p != 0) {
        float* r = red + (size_t)(((p - 1) * 4 + qw) * 64 + lane) * 33;
#pragma unroll
        for (int dt = 0; dt < 2; ++dt)
#pragma unroll
            for (int rr = 0; rr < 16; ++rr) r[dt * 16 + rr] = oacc[dt][rr];
        r[32] = zacc;
    }
    __syncthreads();
    if (p == 0) {
#pragma unroll
        for (int pp = 1; pp < 4; ++pp) {
            const float* r = red + (size_t)(((pp - 1) * 4 + qw) * 64 + lane) * 33;
#pragma unroll
            for (int dt = 0; dt < 2; ++dt)
#pragma unroll
                for (int rr = 0; rr < 16; ++rr) oacc[dt][rr] += r[dt * 16 + rr];
            zacc += r[32];
        }

        const float invl = 1.f / (zacc + KEPS);   // lane il holds inv for row q0+il
#pragma unroll
        for (int r = 0; r < 16; ++r) {
            const int rl  = (r & 3) + 8 * (r >> 2) + 4 * hi;
            const float inv = __shfl(invl, rl);
            Oh[(size_t)(q0 + rl) * DDIM + il]      = oacc[0][r] * inv;
            Oh[(size_t)(q0 + rl) * DDIM + 32 + il] = oacc[1][r] * inv;
        }
    }
}

extern "C" void kernel_launch(void* const* d_in, const int* in_sizes, int n_in,
                              void* d_out, int out_size, void* d_ws, size_t ws_size,
                              hipStream_t stream) {
    const float* q = (const float*)d_in[0];
    const float* k = (const float*)d_in[1];
    const float* v = (const float*)d_in[2];
    float* o = (float*)d_out;
    hipLaunchKernelGGL(rebased_attn_kernel, dim3(256), dim3(1024), 0, stream, q, k, v, o);
}

// Round 8
// 60.631 us; speedup vs baseline: 1.7120x; 1.7120x over previous
//
#include <hip/hip_runtime.h>

typedef __attribute__((ext_vector_type(8))) short bf16x8;
typedef __attribute__((ext_vector_type(16))) float f32x16;

#define SLEN 2048
#define DDIM 64
#define KEPS 1e-6f
#define STR 72                 // shorts per LDS row (144 B): 16B-aligned, spread banks
#define TILES (64 * STR)       // shorts per 64-row tile

// packed fp32x2 -> bf16x2 RNE, single VALU op
__device__ __forceinline__ unsigned cvtpk(float lo, float hi) {
    unsigned r;
    asm("v_cvt_pk_bf16_f32 %0, %1, %2" : "=v"(r) : "v"(lo), "v"(hi));
    return r;
}

__device__ __forceinline__ f32x16 mfma32x32(bf16x8 a, bf16x8 b, f32x16 c) {
    return __builtin_amdgcn_mfma_f32_32x32x16_bf16(a, b, c, 0, 0, 0);
}

// Rebased linear attention, causal, z = rowsum(s^2).
// 512 blocks x 512 threads (2 blocks/CU, uniform work). Block = (head h, pair pg,
// row-half halfb): covers rows [halfb*32, +32) of groups pg AND 31-pg (mirror inside
// block -> uniform 33-tile compute). 8 waves = 2 KV-parities x 2 q-groups x 2 j-subtiles.
// 32x32x16 MFMA, swapped QK^T -> S^T; P repacked via cvt_pk + permlane32_swap;
// double-buffered LDS per parity, ONE barrier per iteration, issue-early staging.
__global__ void __launch_bounds__(512, 4) rebased_attn_kernel(
    const float* __restrict__ Q, const float* __restrict__ K,
    const float* __restrict__ V, float* __restrict__ O)
{
    __shared__ __align__(16) short smem[2 * 2 * 2 * TILES];   // [par][dbuf][K,VT] = 73728 B

    const int bid   = blockIdx.x;
    const int xcd   = bid & 7;                  // head pinned to XCD
    const int r     = bid >> 3;                 // 0..63
    const int h     = xcd | ((r & 1) << 3);     // 0..15
    const int u     = r >> 1;                   // 0..31
    const int pg    = u & 15;                   // mirror pair (pg, 31-pg)
    const int halfb = u >> 4;                   // which 32-row half of each group

    const int tid  = threadIdx.x;
    const int w    = tid >> 6;                  // wave 0..7
    const int lane = tid & 63;
    const int il   = lane & 31;                 // i-col within 32x32 fragment
    const int hi   = lane >> 5;
    const int p    = w >> 2;                    // KV parity 0..1 (== tid>>8)
    const int qsel = (w >> 1) & 1;              // 0 = group pg, 1 = group 31-pg
    const int jb   = w & 1;                     // j-subtile 0..1 within 64-KV tile

    const int grp   = qsel ? (31 - pg) : pg;
    const int q0    = grp * 64 + halfb * 32;    // this wave's 32 q-rows
    const int ktmax = grp;
    const int ktstg = 31 - pg;                  // last tile the block stages

    const float* __restrict__ Qh = Q + (size_t)h * SLEN * DDIM;
    const float* __restrict__ Kh = K + (size_t)h * SLEN * DDIM;
    const float* __restrict__ Vh = V + (size_t)h * SLEN * DDIM;
    float* __restrict__ Oh = O + (size_t)h * SLEN * DDIM;

    // ---- Q fragments (B-frag of 32x32x16): lane holds Q[q0+il][ks*16 + hi*8 + t] ----
    bf16x8 qf[4];
#pragma unroll
    for (int ks = 0; ks < 4; ++ks) {
        const float* src = Qh + (size_t)(q0 + il) * DDIM + ks * 16 + hi * 8;
        float4 a = *reinterpret_cast<const float4*>(src);
        float4 b = *reinterpret_cast<const float4*>(src + 4);
        uint4 uq = make_uint4(cvtpk(a.x, a.y), cvtpk(a.z, a.w),
                              cvtpk(b.x, b.y), cvtpk(b.z, b.w));
        qf[ks] = *reinterpret_cast<bf16x8*>(&uq);
    }

    f32x16 oacc0, oacc1;
#pragma unroll
    for (int rr = 0; rr < 16; ++rr) { oacc0[rr] = 0.f; oacc1[rr] = 0.f; }
    float zacc = 0.f;

    // ---- staging maps (per parity: 256 threads move one 64x64 K + V tile) ----
    const int t255 = tid & 255;
    const int kr  = t255 >> 2;             // K row 0..63
    const int kc  = (t255 & 3) * 16;       // K col chunk (floats)
    const int vj0 = (t255 & 15) * 4;       // V rows (j)
    const int vd0 = (t255 >> 4) * 4;       // V cols (d)

    float4 kv[4], vv[4];
    auto issue_loads = [&](int kt) {
        const float* ks = Kh + (size_t)(kt * 64 + kr) * DDIM + kc;
#pragma unroll
        for (int i = 0; i < 4; ++i) kv[i] = reinterpret_cast<const float4*>(ks)[i];
#pragma unroll
        for (int rr = 0; rr < 4; ++rr)
            vv[rr] = *reinterpret_cast<const float4*>(Vh + (size_t)(kt * 64 + vj0 + rr) * DDIM + vd0);
    };
    auto write_lds = [&](int b) {
        short* kd = &smem[((p * 2 + b) * 2 + 0) * TILES] + kr * STR + kc;
        uint4 o0 = make_uint4(cvtpk(kv[0].x, kv[0].y), cvtpk(kv[0].z, kv[0].w),
                              cvtpk(kv[1].x, kv[1].y), cvtpk(kv[1].z, kv[1].w));
        uint4 o1 = make_uint4(cvtpk(kv[2].x, kv[2].y), cvtpk(kv[2].z, kv[2].w),
                              cvtpk(kv[3].x, kv[3].y), cvtpk(kv[3].z, kv[3].w));
        *reinterpret_cast<uint4*>(kd) = o0;
        *reinterpret_cast<uint4*>(kd + 8) = o1;
        short* vd = &smem[((p * 2 + b) * 2 + 1) * TILES];
#pragma unroll
        for (int c = 0; c < 4; ++c) {
            uint2 pk = make_uint2(
                cvtpk(((const float*)&vv[0])[c], ((const float*)&vv[1])[c]),
                cvtpk(((const float*)&vv[2])[c], ((const float*)&vv[3])[c]));
            *reinterpret_cast<uint2*>(&vd[(vd0 + c) * STR + vj0]) = pk;
        }
    };

    const int T = (ktstg >> 1) + 1;

    // ---- prologue: stage tile kt=p into buf 0 ----
    issue_loads(p);
    write_lds(0);
    __syncthreads();

    for (int t = 0; t < T; ++t) {
        const int kt  = 2 * t + p;
        const int nxt = kt + 2;
        const int cur = t & 1;

        if (nxt <= ktstg) issue_loads(nxt);     // in flight during compute

        if (kt <= ktmax && !(kt == ktmax && jb > halfb)) {
            const bool tri = (kt == ktmax) && (jb == halfb);
            const short* kp = &smem[((p * 2 + cur) * 2 + 0) * TILES];
            const short* vp = &smem[((p * 2 + cur) * 2 + 1) * TILES];
            __builtin_amdgcn_s_setprio(1);
            // ---- QK^T (swapped): S^T[32j x 32i] for my j-subtile ----
            f32x16 s;
#pragma unroll
            for (int rr = 0; rr < 16; ++rr) s[rr] = 0.f;
#pragma unroll
            for (int ks = 0; ks < 4; ++ks) {
                bf16x8 kf = *reinterpret_cast<const bf16x8*>(
                    kp + (jb * 32 + il) * STR + ks * 16 + hi * 8);
                s = mfma32x32(kf, qf[ks], s);
            }
            // lane: S^T[j=(rr&3)+8*(rr>>2)+4*hi][i=il]; pv = (s/8)^2 = s^2/64
#pragma unroll
            for (int rr = 0; rr < 16; ++rr) {
                float x = s[rr];
                x = x * x * 0.015625f;
                if (tri) {
                    int jl = (rr & 3) + 8 * (rr >> 2) + 4 * hi;
                    if (jl > il) x = 0.f;
                }
                s[rr] = x;
                zacc += x;
            }
            // ---- pack P to A-frags (cvt_pk + permlane32_swap), PV MFMAs ----
#pragma unroll
            for (int s16 = 0; s16 < 2; ++s16) {
                unsigned X  = cvtpk(s[8 * s16 + 0], s[8 * s16 + 1]);
                unsigned Xp = cvtpk(s[8 * s16 + 2], s[8 * s16 + 3]);
                unsigned Y  = cvtpk(s[8 * s16 + 4], s[8 * s16 + 5]);
                unsigned Yp = cvtpk(s[8 * s16 + 6], s[8 * s16 + 7]);
                asm("v_permlane32_swap_b32 %0, %1" : "+v"(X), "+v"(Y));
                asm("v_permlane32_swap_b32 %0, %1" : "+v"(Xp), "+v"(Yp));
                uint4 aw = make_uint4(X, Xp, Y, Yp);
                bf16x8 pf = *reinterpret_cast<bf16x8*>(&aw);
                {
                    bf16x8 vf = *reinterpret_cast<const bf16x8*>(
                        vp + (0 * 32 + il) * STR + jb * 32 + s16 * 16 + hi * 8);
                    oacc0 = mfma32x32(pf, vf, oacc0);
                }
                {
                    bf16x8 vf = *reinterpret_cast<const bf16x8*>(
                        vp + (1 * 32 + il) * STR + jb * 32 + s16 * 16 + hi * 8);
                    oacc1 = mfma32x32(pf, vf, oacc1);
                }
            }
            __builtin_amdgcn_s_setprio(0);
        }

        if (nxt <= ktstg) write_lds(cur ^ 1);
        __syncthreads();
    }

    // ---- combine partials across (p, jb) for each (qsel): 4 -> 1 via LDS ----
    zacc += __shfl_xor(zacc, 32);               // both halves hold z[i=il] partial
    float* red = (float*)smem;
    const int slot = p * 2 + jb;                // 0..3; slot 0 is the finalizer
    if (slot != 0) {
        float* rr_ = red + (size_t)((((slot - 1) * 2 + qsel) * 64 + lane) * 33);
#pragma unroll
        for (int rr = 0; rr < 16; ++rr) { rr_[rr] = oacc0[rr]; rr_[16 + rr] = oacc1[rr]; }
        rr_[32] = zacc;
    }
    __syncthreads();
    if (slot == 0) {
#pragma unroll
        for (int pp = 1; pp < 4; ++pp) {
            const float* rr_ = red + (size_t)((((pp - 1) * 2 + qsel) * 64 + lane) * 33);
#pragma unroll
            for (int rr = 0; rr < 16; ++rr) { oacc0[rr] += rr_[rr]; oacc1[rr] += rr_[16 + rr]; }
            zacc += rr_[32];
        }

        const float invl = 1.f / (zacc + KEPS);   // lane il: inv for row q0+il
#pragma unroll
        for (int rr = 0; rr < 16; ++rr) {
            const int rl = (rr & 3) + 8 * (rr >> 2) + 4 * hi;
            const float inv = __shfl(invl, rl);
            Oh[(size_t)(q0 + rl) * DDIM + il]      = oacc0[rr] * inv;
            Oh[(size_t)(q0 + rl) * DDIM + 32 + il] = oacc1[rr] * inv;
        }
    }
}

extern "C" void kernel_launch(void* const* d_in, const int* in_sizes, int n_in,
                              void* d_out, int out_size, void* d_ws, size_t ws_size,
                              hipStream_t stream) {
    const float* q = (const float*)d_in[0];
    const float* k = (const float*)d_in[1];
    const float* v = (const float*)d_in[2];
    float* o = (float*)d_out;
    hipLaunchKernelGGL(rebased_attn_kernel, dim3(512), dim3(512), 0, stream, q, k, v, o);
}

// Round 9
// 35.746 us; speedup vs baseline: 2.9039x; 1.6962x over previous
//
#include <hip/hip_runtime.h>

typedef __attribute__((ext_vector_type(8))) short bf16x8;
typedef __attribute__((ext_vector_type(16))) float f32x16;

#define SLEN 2048
#define DDIM 64
#define NH 16
#define KEPS 1e-6f
#define TILE_B 16384          // bytes per (K 8KB | VT 8KB) tile image in ws and LDS
#define PSTR 72               // prep transpose LDS stride (shorts)

// fp32 -> bf16 RNE scalar
__device__ __forceinline__ short f2bf(float x) {
    unsigned u = __float_as_uint(x);
    unsigned r = (u + 0x7FFFu + ((u >> 16) & 1u)) >> 16;
    return (short)r;
}
// packed fp32x2 -> bf16x2 RNE, single VALU op
__device__ __forceinline__ unsigned cvtpk(float lo, float hi) {
    unsigned r;
    asm("v_cvt_pk_bf16_f32 %0, %1, %2" : "=v"(r) : "v"(lo), "v"(hi));
    return r;
}
__device__ __forceinline__ f32x16 mfma32x32(bf16x8 a, bf16x8 b, f32x16 c) {
    return __builtin_amdgcn_mfma_f32_32x32x16_bf16(a, b, c, 0, 0, 0);
}
// async global->LDS, 16B per lane; LDS dest = uniform base + lane*16
__device__ __forceinline__ void gload16(const void* g, void* l) {
    __builtin_amdgcn_global_load_lds(
        (const __attribute__((address_space(1))) unsigned*)g,
        (__attribute__((address_space(3))) unsigned*)l, 16, 0, 0);
}

// ---------------- prep: build per-tile bf16 LDS images in ws ----------------
// WS[h][kt] (16 KB): K-part chunks c=ks*2+hi: [c][j][8t] = bf16(K[h][kt*64+j][ks*16+hi*8+t])
//                    V-part (+8KB) chunks cv:  [cv][d][8t] = bf16(V[h][kt*64+(cv>>1)*16+(cv&1)*8+t][d])
__global__ void __launch_bounds__(256) prep_kernel(
    const float* __restrict__ K, const float* __restrict__ V, char* __restrict__ WS)
{
    __shared__ short vt[64 * PSTR];
    const int b  = blockIdx.x;            // h*32 + kt
    const int h  = b >> 5;
    const int kt = b & 31;
    const int t  = threadIdx.x;
    const int j  = t >> 2;                // 0..63
    const int ks = t & 3;
    const int c16 = ks * 16;

    char* chunk = WS + (size_t)b * TILE_B;

    {   // K: row j, 16 cols -> two 16B fragment writes
        const float* src = K + ((size_t)h * SLEN + kt * 64 + j) * DDIM + c16;
        float4 a = ((const float4*)src)[0], bb = ((const float4*)src)[1];
        float4 c = ((const float4*)src)[2], d = ((const float4*)src)[3];
        uint4 lo = make_uint4(cvtpk(a.x,a.y), cvtpk(a.z,a.w), cvtpk(bb.x,bb.y), cvtpk(bb.z,bb.w));
        uint4 hi = make_uint4(cvtpk(c.x,c.y), cvtpk(c.z,c.w), cvtpk(d.x,d.y), cvtpk(d.z,d.w));
        *(uint4*)(chunk + ((size_t)((ks*2+0)*64 + j)) * 16) = lo;
        *(uint4*)(chunk + ((size_t)((ks*2+1)*64 + j)) * 16) = hi;
    }
    {   // V: bf16 scatter-transpose into vt[d][j]
        const float* src = V + ((size_t)h * SLEN + kt * 64 + j) * DDIM + c16;
        float4 a = ((const float4*)src)[0], bb = ((const float4*)src)[1];
        float4 c = ((const float4*)src)[2], d = ((const float4*)src)[3];
        float f[16] = {a.x,a.y,a.z,a.w, bb.x,bb.y,bb.z,bb.w, c.x,c.y,c.z,c.w, d.x,d.y,d.z,d.w};
#pragma unroll
        for (int q = 0; q < 16; ++q)
            vt[(c16 + q) * PSTR + j] = f2bf(f[q]);
    }
    __syncthreads();
    {   // gather: d = t>>2, 16 j's -> two 16B fragment writes
        const int d  = t >> 2;
        const int jc = (t & 3) * 16;
        uint4 lo = *(const uint4*)&vt[d * PSTR + jc];
        uint4 hi = *(const uint4*)&vt[d * PSTR + jc + 8];
        char* vbase = chunk + 8192;
        *(uint4*)(vbase + (size_t)(((jc >> 4) * 2 + 0) * 64 + d) * 16) = lo;
        *(uint4*)(vbase + (size_t)(((jc >> 4) * 2 + 1) * 64 + d) * 16) = hi;
    }
}

// ---------------- main: rebased linear attention, causal, z = rowsum(s^2) ----------------
// 512 blocks x 512 threads (2 blocks/CU). Block = (h, pair pg, row-half): rows
// [halfb*32,+32) of groups pg AND 31-pg (uniform 33-tile work). 8 waves =
// 2 KV-parities x 2 q-groups x 2 j-subtiles. 32x32x16 MFMA, swapped QK^T;
// P repacked via cvt_pk + permlane32_swap. Staging: WSP=true -> global_load_lds
// from prepped bf16 tile images (no staging regs); WSP=false -> fp32 reg staging.
template<bool WSP>
__device__ __forceinline__ void attn_body(
    const float* __restrict__ Q, const void* __restrict__ s1,
    const void* __restrict__ s2, float* __restrict__ O)
{
    __shared__ __align__(16) char smem[2][2][TILE_B];   // [parity][dbuf][K|VT] = 64 KB

    const int bid   = blockIdx.x;
    const int xcd   = bid & 7;                  // head pinned to XCD
    const int r     = bid >> 3;
    const int h     = xcd | ((r & 1) << 3);
    const int u     = r >> 1;
    const int pg    = u & 15;
    const int halfb = u >> 4;

    const int tid  = threadIdx.x;
    const int w    = tid >> 6;
    const int lane = tid & 63;
    const int il   = lane & 31;
    const int hi   = lane >> 5;
    const int p    = w >> 2;                    // KV parity (== tid>>8)
    const int qsel = (w >> 1) & 1;
    const int jb   = w & 1;

    const int grp   = qsel ? (31 - pg) : pg;
    const int q0    = grp * 64 + halfb * 32;
    const int ktmax = grp;
    const int ktstg = 31 - pg;

    const float* __restrict__ Qh = Q + (size_t)h * SLEN * DDIM;
    float* __restrict__ Oh = O + (size_t)h * SLEN * DDIM;

    // Q fragments (B-frag of 32x32x16): lane holds Q[q0+il][ks*16+hi*8+t]
    bf16x8 qf[4];
#pragma unroll
    for (int ks = 0; ks < 4; ++ks) {
        const float* src = Qh + (size_t)(q0 + il) * DDIM + ks * 16 + hi * 8;
        float4 a = *reinterpret_cast<const float4*>(src);
        float4 b = *reinterpret_cast<const float4*>(src + 4);
        uint4 uq = make_uint4(cvtpk(a.x, a.y), cvtpk(a.z, a.w),
                              cvtpk(b.x, b.y), cvtpk(b.z, b.w));
        qf[ks] = *reinterpret_cast<bf16x8*>(&uq);
    }

    f32x16 oacc0, oacc1;
#pragma unroll
    for (int rr = 0; rr < 16; ++rr) { oacc0[rr] = 0.f; oacc1[rr] = 0.f; }
    float zacc = 0.f;

    // ---- staging (parity group p = 4 waves; wv = wave within group) ----
    const int wv = w & 3;
    const char* WSh = (const char*)s1 + (size_t)h * 32 * TILE_B;   // WSP path
    // fp32 path maps
    const int t255 = tid & 255;
    const int kr = t255 >> 2, kks = t255 & 3;
    const int vj0 = (t255 & 15) * 4, vd0 = (t255 >> 4) * 4;
    const float* Kf = (const float*)s1;
    const float* Vf = (const float*)s2;
    float4 kv[4], vv[4];

    auto stage_async = [&](int buf, int kt) {   // WSP: pure linear async copy
        const char* g = WSh + (size_t)kt * TILE_B + wv * 4096 + lane * 16;
        char* l = &smem[p][buf][wv * 4096];
        gload16(g,        l);
        gload16(g + 1024, l + 1024);
        gload16(g + 2048, l + 2048);
        gload16(g + 3072, l + 3072);
    };
    auto issue_loads = [&](int kt) {            // fp32 fallback
        const float* ks = Kf + ((size_t)h * SLEN + kt * 64 + kr) * DDIM + kks * 16;
#pragma unroll
        for (int i = 0; i < 4; ++i) kv[i] = reinterpret_cast<const float4*>(ks)[i];
#pragma unroll
        for (int rr = 0; rr < 4; ++rr)
            vv[rr] = *reinterpret_cast<const float4*>(
                Vf + ((size_t)h * SLEN + kt * 64 + vj0 + rr) * DDIM + vd0);
    };
    auto write_lds = [&](int buf) {             // fp32 fallback: blocked layout
        char* kd = &smem[p][buf][0];
        uint4 lo = make_uint4(cvtpk(kv[0].x,kv[0].y), cvtpk(kv[0].z,kv[0].w),
                              cvtpk(kv[1].x,kv[1].y), cvtpk(kv[1].z,kv[1].w));
        uint4 hii = make_uint4(cvtpk(kv[2].x,kv[2].y), cvtpk(kv[2].z,kv[2].w),
                               cvtpk(kv[3].x,kv[3].y), cvtpk(kv[3].z,kv[3].w));
        *(uint4*)(kd + (size_t)((kks*2+0)*64 + kr) * 16) = lo;
        *(uint4*)(kd + (size_t)((kks*2+1)*64 + kr) * 16) = hii;
        char* vd = &smem[p][buf][8192];
        const int cv  = ((vj0 >> 4) * 2) + ((vj0 >> 3) & 1);
        const int tof = vj0 & 7;
#pragma unroll
        for (int c = 0; c < 4; ++c) {
            uint2 pk = make_uint2(
                cvtpk(((const float*)&vv[0])[c], ((const float*)&vv[1])[c]),
                cvtpk(((const float*)&vv[2])[c], ((const float*)&vv[3])[c]));
            *(uint2*)(vd + (size_t)(cv * 64 + vd0 + c) * 16 + tof * 2) = pk;
        }
    };

    const int T = (ktstg >> 1) + 1;

    // prologue
    if (WSP) { stage_async(0, p); }
    else     { issue_loads(p); write_lds(0); }
    __syncthreads();

    for (int t = 0; t < T; ++t) {
        const int kt  = 2 * t + p;
        const int nxt = kt + 2;
        const int cur = t & 1;

        if (nxt <= ktstg) { if (WSP) stage_async(cur ^ 1, nxt); else issue_loads(nxt); }

        if (kt <= ktmax && !(kt == ktmax && jb > halfb)) {
            const bool tri = (kt == ktmax) && (jb == halfb);
            const short* kp = (const short*)&smem[p][cur][0];
            const short* vp = (const short*)&smem[p][cur][8192];
            __builtin_amdgcn_s_setprio(1);
            // QK^T (swapped): S^T[32j x 32i] for my j-subtile
            f32x16 s;
#pragma unroll
            for (int rr = 0; rr < 16; ++rr) s[rr] = 0.f;
#pragma unroll
            for (int ks = 0; ks < 4; ++ks) {
                bf16x8 kf = *reinterpret_cast<const bf16x8*>(
                    kp + (size_t)((ks*2+hi)*64 + jb*32 + il) * 8);
                s = mfma32x32(kf, qf[ks], s);
            }
            // lane: S^T[j=(rr&3)+8*(rr>>2)+4*hi][i=il]; pv = (s/8)^2
#pragma unroll
            for (int rr = 0; rr < 16; ++rr) {
                float x = s[rr];
                x = x * x * 0.015625f;
                if (tri) {
                    int jl = (rr & 3) + 8 * (rr >> 2) + 4 * hi;
                    if (jl > il) x = 0.f;
                }
                s[rr] = x;
                zacc += x;
            }
            // pack P (cvt_pk + permlane32_swap) and PV MFMAs
#pragma unroll
            for (int s16 = 0; s16 < 2; ++s16) {
                unsigned X  = cvtpk(s[8*s16+0], s[8*s16+1]);
                unsigned Xp = cvtpk(s[8*s16+2], s[8*s16+3]);
                unsigned Y  = cvtpk(s[8*s16+4], s[8*s16+5]);
                unsigned Yp = cvtpk(s[8*s16+6], s[8*s16+7]);
                asm("v_permlane32_swap_b32 %0, %1" : "+v"(X), "+v"(Y));
                asm("v_permlane32_swap_b32 %0, %1" : "+v"(Xp), "+v"(Yp));
                uint4 aw = make_uint4(X, Xp, Y, Yp);
                bf16x8 pf = *reinterpret_cast<bf16x8*>(&aw);
                {
                    bf16x8 vf = *reinterpret_cast<const bf16x8*>(
                        vp + (size_t)(((jb*2+s16)*2+hi)*64 + 0*32 + il) * 8);
                    oacc0 = mfma32x32(pf, vf, oacc0);
                }
                {
                    bf16x8 vf = *reinterpret_cast<const bf16x8*>(
                        vp + (size_t)(((jb*2+s16)*2+hi)*64 + 1*32 + il) * 8);
                    oacc1 = mfma32x32(pf, vf, oacc1);
                }
            }
            __builtin_amdgcn_s_setprio(0);
        }

        if (!WSP && nxt <= ktstg) write_lds(cur ^ 1);
        __syncthreads();
    }

    // combine partials across (p,jb) per qsel: 4 -> 1 via LDS (stride-33 floats)
    zacc += __shfl_xor(zacc, 32);
    float* red = (float*)smem;
    const int slot = p * 2 + jb;
    if (slot != 0) {
        float* rr_ = red + (size_t)((((slot - 1) * 2 + qsel) * 64 + lane) * 33);
#pragma unroll
        for (int rr = 0; rr < 16; ++rr) { rr_[rr] = oacc0[rr]; rr_[16 + rr] = oacc1[rr]; }
        rr_[32] = zacc;
    }
    __syncthreads();
    if (slot == 0) {
#pragma unroll
        for (int pp = 1; pp < 4; ++pp) {
            const float* rr_ = red + (size_t)((((pp - 1) * 2 + qsel) * 64 + lane) * 33);
#pragma unroll
            for (int rr = 0; rr < 16; ++rr) { oacc0[rr] += rr_[rr]; oacc1[rr] += rr_[16 + rr]; }
            zacc += rr_[32];
        }
        const float invl = 1.f / (zacc + KEPS);   // lane il: inv for row q0+il
#pragma unroll
        for (int rr = 0; rr < 16; ++rr) {
            const int rl = (rr & 3) + 8 * (rr >> 2) + 4 * hi;
            const float inv = __shfl(invl, rl);
            Oh[(size_t)(q0 + rl) * DDIM + il]      = oacc0[rr] * inv;
            Oh[(size_t)(q0 + rl) * DDIM + 32 + il] = oacc1[rr] * inv;
        }
    }
}

__global__ void __launch_bounds__(512, 4) attn_ws(
    const float* __restrict__ Q, const char* __restrict__ WS, float* __restrict__ O)
{
    attn_body<true>(Q, WS, nullptr, O);
}
__global__ void __launch_bounds__(512, 4) attn_fp32(
    const float* __restrict__ Q, const float* __restrict__ K,
    const float* __restrict__ V, float* __restrict__ O)
{
    attn_body<false>(Q, K, V, O);
}

extern "C" void kernel_launch(void* const* d_in, const int* in_sizes, int n_in,
                              void* d_out, int out_size, void* d_ws, size_t ws_size,
                              hipStream_t stream) {
    const float* q = (const float*)d_in[0];
    const float* k = (const float*)d_in[1];
    const float* v = (const float*)d_in[2];
    float* o = (float*)d_out;

    const size_t need = (size_t)NH * 32 * TILE_B;   // 8 MB
    if (ws_size >= need) {
        char* ws = (char*)d_ws;
        hipLaunchKernelGGL(prep_kernel, dim3(NH * 32), dim3(256), 0, stream, k, v, ws);
        hipLaunchKernelGGL(attn_ws, dim3(512), dim3(512), 0, stream, q, ws, o);
    } else {
        hipLaunchKernelGGL(attn_fp32, dim3(512), dim3(512), 0, stream, q, k, v, o);
    }
}

// Round 10
// 30.775 us; speedup vs baseline: 3.3729x; 1.1615x over previous
//
#include <hip/hip_runtime.h>

typedef __attribute__((ext_vector_type(8))) short bf16x8;
typedef __attribute__((ext_vector_type(16))) float f32x16;

#define SLEN 2048
#define DDIM 64
#define NH 16
#define KEPS 1e-6f
#define TILE_B 16384          // bytes per (K 8KB | VT 8KB) tile image in ws
#define PSTR 72               // prep transpose LDS stride (shorts)

// fp32 -> bf16 RNE scalar
__device__ __forceinline__ short f2bf(float x) {
    unsigned u = __float_as_uint(x);
    unsigned r = (u + 0x7FFFu + ((u >> 16) & 1u)) >> 16;
    return (short)r;
}
// packed fp32x2 -> bf16x2 RNE, single VALU op
__device__ __forceinline__ unsigned cvtpk(float lo, float hi) {
    unsigned r;
    asm("v_cvt_pk_bf16_f32 %0, %1, %2" : "=v"(r) : "v"(lo), "v"(hi));
    return r;
}
__device__ __forceinline__ f32x16 mfma32x32(bf16x8 a, bf16x8 b, f32x16 c) {
    return __builtin_amdgcn_mfma_f32_32x32x16_bf16(a, b, c, 0, 0, 0);
}

// ---------------- prep: build per-tile bf16 fragment images in ws (UNCHANGED, proven) ----
// WS[h][kt] (16 KB): K chunks c=ks*2+hi: [c][j][8t] = bf16(K[h][kt*64+j][ks*16+hi*8+t])
//                    V (+8KB) chunks cv:  [cv][d][8t] = bf16(V[h][kt*64+(cv>>1)*16+(cv&1)*8+t][d])
__global__ void __launch_bounds__(256) prep_kernel(
    const float* __restrict__ K, const float* __restrict__ V, char* __restrict__ WS)
{
    __shared__ short vt[64 * PSTR];
    const int b  = blockIdx.x;            // h*32 + kt
    const int h  = b >> 5;
    const int kt = b & 31;
    const int t  = threadIdx.x;
    const int j  = t >> 2;                // 0..63
    const int ks = t & 3;
    const int c16 = ks * 16;

    char* chunk = WS + (size_t)b * TILE_B;

    {   // K: row j, 16 cols -> two 16B fragment writes
        const float* src = K + ((size_t)h * SLEN + kt * 64 + j) * DDIM + c16;
        float4 a = ((const float4*)src)[0], bb = ((const float4*)src)[1];
        float4 c = ((const float4*)src)[2], d = ((const float4*)src)[3];
        uint4 lo = make_uint4(cvtpk(a.x,a.y), cvtpk(a.z,a.w), cvtpk(bb.x,bb.y), cvtpk(bb.z,bb.w));
        uint4 hi = make_uint4(cvtpk(c.x,c.y), cvtpk(c.z,c.w), cvtpk(d.x,d.y), cvtpk(d.z,d.w));
        *(uint4*)(chunk + ((size_t)((ks*2+0)*64 + j)) * 16) = lo;
        *(uint4*)(chunk + ((size_t)((ks*2+1)*64 + j)) * 16) = hi;
    }
    {   // V: bf16 scatter-transpose into vt[d][j]
        const float* src = V + ((size_t)h * SLEN + kt * 64 + j) * DDIM + c16;
        float4 a = ((const float4*)src)[0], bb = ((const float4*)src)[1];
        float4 c = ((const float4*)src)[2], d = ((const float4*)src)[3];
        float f[16] = {a.x,a.y,a.z,a.w, bb.x,bb.y,bb.z,bb.w, c.x,c.y,c.z,c.w, d.x,d.y,d.z,d.w};
#pragma unroll
        for (int q = 0; q < 16; ++q)
            vt[(c16 + q) * PSTR + j] = f2bf(f[q]);
    }
    __syncthreads();
    {   // gather: two 16B fragment writes
        const int d  = t >> 2;
        const int jc = (t & 3) * 16;
        uint4 lo = *(const uint4*)&vt[d * PSTR + jc];
        uint4 hi = *(const uint4*)&vt[d * PSTR + jc + 8];
        char* vbase = chunk + 8192;
        *(uint4*)(vbase + (size_t)(((jc >> 4) * 2 + 0) * 64 + d) * 16) = lo;
        *(uint4*)(vbase + (size_t)(((jc >> 4) * 2 + 1) * 64 + d) * 16) = hi;
    }
}

// ---------------- main: NO LDS staging, NO barriers in loop ----------------
// 512 blocks x 512 threads (2 blocks/CU, 16 waves/CU). Block = (xcd-pinned head h,
// CU-slot c): slices 2c (g=c, half=0) and 63-2c (g=31-c, half=1) -> every block
// identical work. 8 waves = 2 msel x 2 jb x 2 tile-parity e; each wave: 32 q-rows,
// fragments loaded straight from prepped ws images into VGPRs (coalesced, L2-hot),
// K prefetched one tile ahead, V issued at tile start, consumed at PV. One barrier
// at the end for the 4-way partial reduction per msel group.
__global__ void __launch_bounds__(512, 4) attn_main(
    const float* __restrict__ Q, const char* __restrict__ WS, float* __restrict__ O)
{
    __shared__ float red[2][3][64][33];   // 50688 B, reduction only

    const int bid = blockIdx.x;
    const int xcd = bid & 7;
    const int m   = bid >> 3;             // 0..63
    const int h   = xcd | ((m & 1) << 3); // head pinned to XCD
    const int c   = m >> 1;               // 0..31

    const int tid  = threadIdx.x;
    const int w    = tid >> 6;
    const int lane = tid & 63;
    const int il   = lane & 31;
    const int hi   = lane >> 5;
    const int msel = w >> 2;              // 0: slice 2c, 1: slice 63-2c
    const int jb   = (w >> 1) & 1;        // j-subtile within 64-KV tile
    const int e    = w & 1;               // tile parity (kt = e, e+2, ...)

    const int g    = msel ? (31 - c) : c;
    const int half = msel;                // row-half within group
    const int q0   = g * 64 + half * 32;

    const float* __restrict__ Qh = Q + (size_t)h * SLEN * DDIM;
    float* __restrict__ Oh = O + (size_t)h * SLEN * DDIM;
    const char* __restrict__ WSh = WS + (size_t)h * 32 * TILE_B;

    // ---- Q fragments (B-frag of 32x32x16): lane holds Q[q0+il][ks*16+hi*8+t] ----
    bf16x8 qf[4];
#pragma unroll
    for (int ks = 0; ks < 4; ++ks) {
        const float* src = Qh + (size_t)(q0 + il) * DDIM + ks * 16 + hi * 8;
        float4 a = *reinterpret_cast<const float4*>(src);
        float4 b = *reinterpret_cast<const float4*>(src + 4);
        uint4 uq = make_uint4(cvtpk(a.x, a.y), cvtpk(a.z, a.w),
                              cvtpk(b.x, b.y), cvtpk(b.z, b.w));
        qf[ks] = *reinterpret_cast<bf16x8*>(&uq);
    }

    f32x16 oacc0, oacc1;
#pragma unroll
    for (int rr = 0; rr < 16; ++rr) { oacc0[rr] = 0.f; oacc1[rr] = 0.f; }
    float zacc = 0.f;

    // per-lane fragment byte offsets inside a tile image
    const int koff = (hi * 64 + jb * 32 + il) * 16;                 // + ks*2048
    const int voff = 8192 + ((jb * 2 * 2 + hi) * 64 + il) * 16;     // + s16*2048 + dt*512

    const int ktend = g - ((jb > half) ? 1 : 0);   // jb>half: diagonal tile fully masked

    if (e <= ktend) {
        // prologue: K frags for first tile
        const char* kb = WSh + (size_t)e * TILE_B + koff;
        bf16x8 kf0 = *(const bf16x8*)(kb);
        bf16x8 kf1 = *(const bf16x8*)(kb + 2048);
        bf16x8 kf2 = *(const bf16x8*)(kb + 4096);
        bf16x8 kf3 = *(const bf16x8*)(kb + 6144);

        for (int kt = e; kt <= ktend; kt += 2) {
            const char* tb = WSh + (size_t)kt * TILE_B;
            // V frags for this tile: issued now, consumed ~end of iteration
            const char* vb = tb + voff;
            bf16x8 v00 = *(const bf16x8*)(vb);            // s16=0, dt=0
            bf16x8 v01 = *(const bf16x8*)(vb + 512);      // s16=0, dt=1
            bf16x8 v10 = *(const bf16x8*)(vb + 2048);     // s16=1, dt=0
            bf16x8 v11 = *(const bf16x8*)(vb + 2560);     // s16=1, dt=1

            // ---- QK^T (swapped): S^T[32j x 32i] ----
            f32x16 s;
#pragma unroll
            for (int rr = 0; rr < 16; ++rr) s[rr] = 0.f;
            s = mfma32x32(kf0, qf[0], s);
            s = mfma32x32(kf1, qf[1], s);
            s = mfma32x32(kf2, qf[2], s);
            s = mfma32x32(kf3, qf[3], s);

            // prefetch K frags for tile kt+2 (consumed next iteration)
            if (kt + 2 <= ktend) {
                const char* nb = WSh + (size_t)(kt + 2) * TILE_B + koff;
                kf0 = *(const bf16x8*)(nb);
                kf1 = *(const bf16x8*)(nb + 2048);
                kf2 = *(const bf16x8*)(nb + 4096);
                kf3 = *(const bf16x8*)(nb + 6144);
            }

            // lane: S^T[j=(rr&3)+8*(rr>>2)+4*hi][i=il]; pv = (s/8)^2 = s^2/64
            const bool tri = (kt == g) && (jb == half);
#pragma unroll
            for (int rr = 0; rr < 16; ++rr) {
                float x = s[rr];
                x = x * x * 0.015625f;
                if (tri) {
                    int jl = (rr & 3) + 8 * (rr >> 2) + 4 * hi;
                    if (jl > il) x = 0.f;
                }
                s[rr] = x;
            }
            {   // short z chain (pairwise tree)
                float a0 = (s[0] + s[1]) + (s[2] + s[3]);
                float a1 = (s[4] + s[5]) + (s[6] + s[7]);
                float a2 = (s[8] + s[9]) + (s[10] + s[11]);
                float a3 = (s[12] + s[13]) + (s[14] + s[15]);
                zacc += (a0 + a1) + (a2 + a3);
            }

            // ---- pack P (cvt_pk + permlane32_swap), PV MFMAs ----
            {
                unsigned X  = cvtpk(s[0], s[1]);
                unsigned Xp = cvtpk(s[2], s[3]);
                unsigned Y  = cvtpk(s[4], s[5]);
                unsigned Yp = cvtpk(s[6], s[7]);
                asm("v_permlane32_swap_b32 %0, %1" : "+v"(X), "+v"(Y));
                asm("v_permlane32_swap_b32 %0, %1" : "+v"(Xp), "+v"(Yp));
                uint4 aw = make_uint4(X, Xp, Y, Yp);
                bf16x8 pf = *reinterpret_cast<bf16x8*>(&aw);
                oacc0 = mfma32x32(pf, v00, oacc0);
                oacc1 = mfma32x32(pf, v01, oacc1);
            }
            {
                unsigned X  = cvtpk(s[8],  s[9]);
                unsigned Xp = cvtpk(s[10], s[11]);
                unsigned Y  = cvtpk(s[12], s[13]);
                unsigned Yp = cvtpk(s[14], s[15]);
                asm("v_permlane32_swap_b32 %0, %1" : "+v"(X), "+v"(Y));
                asm("v_permlane32_swap_b32 %0, %1" : "+v"(Xp), "+v"(Yp));
                uint4 aw = make_uint4(X, Xp, Y, Yp);
                bf16x8 pf = *reinterpret_cast<bf16x8*>(&aw);
                oacc0 = mfma32x32(pf, v10, oacc0);
                oacc1 = mfma32x32(pf, v11, oacc1);
            }
        }
    }

    // ---- combine 4 partials per msel group via LDS (stride-33: conflict-free) ----
    zacc += __shfl_xor(zacc, 32);         // fold hi halves: z partial for row q0+il
    const int sw = w & 3;                 // (jb,e) slot within msel group
    if (sw != 0) {
        float* r = &red[msel][sw - 1][lane][0];
#pragma unroll
        for (int rr = 0; rr < 16; ++rr) { r[rr] = oacc0[rr]; r[16 + rr] = oacc1[rr]; }
        r[32] = zacc;
    }
    __syncthreads();
    if (sw == 0) {
#pragma unroll
        for (int pp = 0; pp < 3; ++pp) {
            const float* r = &red[msel][pp][lane][0];
#pragma unroll
            for (int rr = 0; rr < 16; ++rr) { oacc0[rr] += r[rr]; oacc1[rr] += r[16 + rr]; }
            zacc += r[32];
        }
        const float invl = 1.f / (zacc + KEPS);   // lane il: inv for row q0+il
#pragma unroll
        for (int rr = 0; rr < 16; ++rr) {
            const int rl = (rr & 3) + 8 * (rr >> 2) + 4 * hi;
            const float inv = __shfl(invl, rl);
            Oh[(size_t)(q0 + rl) * DDIM + il]      = oacc0[rr] * inv;
            Oh[(size_t)(q0 + rl) * DDIM + 32 + il] = oacc1[rr] * inv;
        }
    }
}

// ---- correctness-only fallback when ws is unavailable (never observed) ----
__global__ void __launch_bounds__(512, 4) attn_fp32(
    const float* __restrict__ Q, const float* __restrict__ K,
    const float* __restrict__ V, float* __restrict__ O)
{
    __shared__ float red[2][3][64][33];

    const int bid = blockIdx.x;
    const int xcd = bid & 7;
    const int m   = bid >> 3;
    const int h   = xcd | ((m & 1) << 3);
    const int c   = m >> 1;

    const int tid  = threadIdx.x;
    const int w    = tid >> 6;
    const int lane = tid & 63;
    const int il   = lane & 31;
    const int hi   = lane >> 5;
    const int msel = w >> 2;
    const int jb   = (w >> 1) & 1;
    const int e    = w & 1;

    const int g    = msel ? (31 - c) : c;
    const int half = msel;
    const int q0   = g * 64 + half * 32;

    const float* Qh = Q + (size_t)h * SLEN * DDIM;
    const float* Kh = K + (size_t)h * SLEN * DDIM;
    const float* Vh = V + (size_t)h * SLEN * DDIM;
    float* Oh = O + (size_t)h * SLEN * DDIM;

    bf16x8 qf[4];
#pragma unroll
    for (int ks = 0; ks < 4; ++ks) {
        const float* src = Qh + (size_t)(q0 + il) * DDIM + ks * 16 + hi * 8;
        float4 a = *reinterpret_cast<const float4*>(src);
        float4 b = *reinterpret_cast<const float4*>(src + 4);
        uint4 uq = make_uint4(cvtpk(a.x, a.y), cvtpk(a.z, a.w),
                              cvtpk(b.x, b.y), cvtpk(b.z, b.w));
        qf[ks] = *reinterpret_cast<bf16x8*>(&uq);
    }

    f32x16 oacc0, oacc1;
#pragma unroll
    for (int rr = 0; rr < 16; ++rr) { oacc0[rr] = 0.f; oacc1[rr] = 0.f; }
    float zacc = 0.f;

    const int ktend = g - ((jb > half) ? 1 : 0);

    for (int kt = e; kt <= ktend; kt += 2) {
        f32x16 s;
#pragma unroll
        for (int rr = 0; rr < 16; ++rr) s[rr] = 0.f;
#pragma unroll
        for (int ks = 0; ks < 4; ++ks) {
            const float* src = Kh + (size_t)(kt * 64 + jb * 32 + il) * DDIM + ks * 16 + hi * 8;
            float4 a = *reinterpret_cast<const float4*>(src);
            float4 b = *reinterpret_cast<const float4*>(src + 4);
            uint4 uk = make_uint4(cvtpk(a.x, a.y), cvtpk(a.z, a.w),
                                  cvtpk(b.x, b.y), cvtpk(b.z, b.w));
            s = mfma32x32(*reinterpret_cast<bf16x8*>(&uk), qf[ks], s);
        }
        const bool tri = (kt == g) && (jb == half);
#pragma unroll
        for (int rr = 0; rr < 16; ++rr) {
            float x = s[rr];
            x = x * x * 0.015625f;
            if (tri) {
                int jl = (rr & 3) + 8 * (rr >> 2) + 4 * hi;
                if (jl > il) x = 0.f;
            }
            s[rr] = x;
            zacc += x;
        }
#pragma unroll
        for (int s16 = 0; s16 < 2; ++s16) {
            unsigned X  = cvtpk(s[8*s16+0], s[8*s16+1]);
            unsigned Xp = cvtpk(s[8*s16+2], s[8*s16+3]);
            unsigned Y  = cvtpk(s[8*s16+4], s[8*s16+5]);
            unsigned Yp = cvtpk(s[8*s16+6], s[8*s16+7]);
            asm("v_permlane32_swap_b32 %0, %1" : "+v"(X), "+v"(Y));
            asm("v_permlane32_swap_b32 %0, %1" : "+v"(Xp), "+v"(Yp));
            uint4 aw = make_uint4(X, Xp, Y, Yp);
            bf16x8 pf = *reinterpret_cast<bf16x8*>(&aw);
#pragma unroll
            for (int dt = 0; dt < 2; ++dt) {
                // V^T fragment gathered scalar (slow, correctness only)
                float v8[8];
#pragma unroll
                for (int t = 0; t < 8; ++t)
                    v8[t] = Vh[(size_t)(kt * 64 + (jb * 2 + s16) * 16 + hi * 8 + t) * DDIM + dt * 32 + il];
                uint4 uv = make_uint4(cvtpk(v8[0], v8[1]), cvtpk(v8[2], v8[3]),
                                      cvtpk(v8[4], v8[5]), cvtpk(v8[6], v8[7]));
                bf16x8 vf = *reinterpret_cast<bf16x8*>(&uv);
                if (dt == 0) oacc0 = mfma32x32(pf, vf, oacc0);
                else         oacc1 = mfma32x32(pf, vf, oacc1);
            }
        }
    }

    zacc += __shfl_xor(zacc, 32);
    const int sw = w & 3;
    if (sw != 0) {
        float* r = &red[msel][sw - 1][lane][0];
#pragma unroll
        for (int rr = 0; rr < 16; ++rr) { r[rr] = oacc0[rr]; r[16 + rr] = oacc1[rr]; }
        r[32] = zacc;
    }
    __syncthreads();
    if (sw == 0) {
#pragma unroll
        for (int pp = 0; pp < 3; ++pp) {
            const float* r = &red[msel][pp][lane][0];
#pragma unroll
            for (int rr = 0; rr < 16; ++rr) { oacc0[rr] += r[rr]; oacc1[rr] += r[16 + rr]; }
            zacc += r[32];
        }
        const float invl = 1.f / (zacc + KEPS);
#pragma unroll
        for (int rr = 0; rr < 16; ++rr) {
            const int rl = (rr & 3) + 8 * (rr >> 2) + 4 * hi;
            const float inv = __shfl(invl, rl);
            Oh[(size_t)(q0 + rl) * DDIM + il]      = oacc0[rr] * inv;
            Oh[(size_t)(q0 + rl) * DDIM + 32 + il] = oacc1[rr] * inv;
        }
    }
}

extern "C" void kernel_launch(void* const* d_in, const int* in_sizes, int n_in,
                              void* d_out, int out_size, void* d_ws, size_t ws_size,
                              hipStream_t stream) {
    const float* q = (const float*)d_in[0];
    const float* k = (const float*)d_in[1];
    const float* v = (const float*)d_in[2];
    float* o = (float*)d_out;

    const size_t need = (size_t)NH * 32 * TILE_B;   // 8 MB
    if (ws_size >= need) {
        char* ws = (char*)d_ws;
        hipLaunchKernelGGL(prep_kernel, dim3(NH * 32), dim3(256), 0, stream, k, v, ws);
        hipLaunchKernelGGL(attn_main, dim3(512), dim3(512), 0, stream, q, ws, o);
    } else {
        hipLaunchKernelGGL(attn_fp32, dim3(512), dim3(512), 0, stream, q, k, v, o);
    }
}